// Round 5
// baseline (4129.140 us; speedup 1.0000x reference)
//
#include <hip/hip_runtime.h>
#include <hip/hip_bf16.h>
#include <math.h>

// Model dims
#define BB     16
#define LL     197
#define DD     384
#define DEPTH  24
#define DI     768
#define DSN    16
#define DTR    24
#define NC     1000
#define TT     (BB*LL)      // 3152 tokens
#define NPATCH 196
#define EPSV   1e-5f

// chunked scan config: chunks of 32 tokens, last chunk 37 (5*32+37=197)
#define NCHUNK 6
#define CH     32

typedef __attribute__((ext_vector_type(8))) short short8;
typedef __attribute__((ext_vector_type(4))) float f32x4;

__device__ __forceinline__ short f2bf(float f) {
  union { float f; unsigned u; } v; v.f = f;
  unsigned u = v.u + 0x7fffu + ((v.u >> 16) & 1u);
  return (short)(u >> 16);
}

// ---------------------------------------------------------------------------
// init
// ---------------------------------------------------------------------------
__global__ __launch_bounds__(256) void k_init(const float* __restrict__ cls,
                                              const float* __restrict__ pos,
                                              float* __restrict__ res,
                                              float* __restrict__ hid) {
  int i = blockIdx.x * 256 + threadIdx.x;
  if (i < TT * DD) res[i] = 0.f;
  if (i < BB * DD) {
    int b = i / DD, d = i % DD;
    hid[(size_t)(b * LL) * DD + d] = cls[d] + pos[d];
  }
}

// ---------------------------------------------------------------------------
// patch embed: bf16 MFMA GEMM with fused im2col.
// ---------------------------------------------------------------------------
__global__ __launch_bounds__(256) void k_patch(const float* __restrict__ x,
                                               const float* __restrict__ pw,
                                               const float* __restrict__ pb,
                                               const float* __restrict__ pos,
                                               float* __restrict__ hid) {
  __shared__ short sA[64 * 40];
  __shared__ short sB[64 * 40];
  const int tid = threadIdx.x;
  const int m0 = blockIdx.x * 64, n0 = blockIdx.y * 64;
  const int srow = tid >> 2;
  const int skq = (tid & 3) * 8;
  const int lane = tid & 63, w = tid >> 6;
  const int wm = (w >> 1) * 32, wn = (w & 1) * 32;
  const int fr = lane & 15;
  const int fk = (lane >> 4) * 8;
  f32x4 acc[2][2] = {};
  const int m = m0 + srow;
  const int b = m / NPATCH;
  const int p = m % NPATCH;
  const int ph = p / 14, pwi = p % 14;
  const float* Wrow = pw + (size_t)(n0 + srow) * 768 + skq;
  for (int k0 = 0; k0 < 768; k0 += 32) {
    int k = k0 + skq;
    int c = k >> 8, rr = (k >> 4) & 15, kw = k & 15;
    const float* xrow = &x[(size_t)(((b * 3 + c) * 224) + (ph * 16 + rr)) * 224 +
                           (pwi * 16 + kw)];
    float4 a0 = *(const float4*)&xrow[0];
    float4 a1 = *(const float4*)&xrow[4];
    float4 b0 = *(const float4*)&Wrow[k0];
    float4 b1 = *(const float4*)&Wrow[k0 + 4];
    short8 av = {f2bf(a0.x), f2bf(a0.y), f2bf(a0.z), f2bf(a0.w),
                 f2bf(a1.x), f2bf(a1.y), f2bf(a1.z), f2bf(a1.w)};
    short8 bv = {f2bf(b0.x), f2bf(b0.y), f2bf(b0.z), f2bf(b0.w),
                 f2bf(b1.x), f2bf(b1.y), f2bf(b1.z), f2bf(b1.w)};
    *(short8*)&sA[srow * 40 + skq] = av;
    *(short8*)&sB[srow * 40 + skq] = bv;
    __syncthreads();
    short8 af0 = *(const short8*)&sA[(wm + fr) * 40 + fk];
    short8 af1 = *(const short8*)&sA[(wm + 16 + fr) * 40 + fk];
    short8 bf0 = *(const short8*)&sB[(wn + fr) * 40 + fk];
    short8 bf1 = *(const short8*)&sB[(wn + 16 + fr) * 40 + fk];
    acc[0][0] = __builtin_amdgcn_mfma_f32_16x16x32_bf16(af0, bf0, acc[0][0], 0, 0, 0);
    acc[0][1] = __builtin_amdgcn_mfma_f32_16x16x32_bf16(af0, bf1, acc[0][1], 0, 0, 0);
    acc[1][0] = __builtin_amdgcn_mfma_f32_16x16x32_bf16(af1, bf0, acc[1][0], 0, 0, 0);
    acc[1][1] = __builtin_amdgcn_mfma_f32_16x16x32_bf16(af1, bf1, acc[1][1], 0, 0, 0);
    __syncthreads();
  }
#pragma unroll
  for (int i = 0; i < 2; i++)
#pragma unroll
    for (int j = 0; j < 2; j++)
#pragma unroll
      for (int q = 0; q < 4; q++) {
        int mm = m0 + wm + i * 16 + (lane >> 4) * 4 + q;
        int nn = n0 + wn + j * 16 + (lane & 15);
        int b2 = mm / NPATCH, pp = mm % NPATCH;
        int tok = b2 * LL + 1 + pp;
        hid[(size_t)tok * DD + nn] = acc[i][j][q] + pb[nn] + pos[(size_t)(1 + pp) * DD + nn];
      }
}

// ---------------------------------------------------------------------------
// bf16 MFMA GEMM: C[M,N] = A[M,K] * W[N,K]^T
// ---------------------------------------------------------------------------
__global__ __launch_bounds__(256) void k_gemm_mfma(const float* __restrict__ A, int lda,
                                                   const float* __restrict__ W, int ldb,
                                                   float* __restrict__ C, int ldc,
                                                   int M, int N, int K) {
  __shared__ short sA[64 * 40];
  __shared__ short sB[64 * 40];
  const int tid = threadIdx.x;
  const int m0 = blockIdx.x * 64, n0 = blockIdx.y * 64;
  const int srow = tid >> 2;
  const int skq = (tid & 3) * 8;
  const int lane = tid & 63, w = tid >> 6;
  const int wm = (w >> 1) * 32, wn = (w & 1) * 32;
  const int fr = lane & 15;
  const int fk = (lane >> 4) * 8;
  f32x4 acc[2][2] = {};
  const int am = m0 + srow;
  const bool aok = am < M;
  const float* Arow = A + (size_t)am * lda + skq;
  const float* Wrow = W + (size_t)(n0 + srow) * ldb + skq;
  for (int k0 = 0; k0 < K; k0 += 32) {
    float4 a0 = {0, 0, 0, 0}, a1 = {0, 0, 0, 0};
    if (aok) {
      a0 = *(const float4*)&Arow[k0];
      a1 = *(const float4*)&Arow[k0 + 4];
    }
    float4 b0 = *(const float4*)&Wrow[k0];
    float4 b1 = *(const float4*)&Wrow[k0 + 4];
    short8 av = {f2bf(a0.x), f2bf(a0.y), f2bf(a0.z), f2bf(a0.w),
                 f2bf(a1.x), f2bf(a1.y), f2bf(a1.z), f2bf(a1.w)};
    short8 bv = {f2bf(b0.x), f2bf(b0.y), f2bf(b0.z), f2bf(b0.w),
                 f2bf(b1.x), f2bf(b1.y), f2bf(b1.z), f2bf(b1.w)};
    *(short8*)&sA[srow * 40 + skq] = av;
    *(short8*)&sB[srow * 40 + skq] = bv;
    __syncthreads();
    short8 af0 = *(const short8*)&sA[(wm + fr) * 40 + fk];
    short8 af1 = *(const short8*)&sA[(wm + 16 + fr) * 40 + fk];
    short8 bf0 = *(const short8*)&sB[(wn + fr) * 40 + fk];
    short8 bf1 = *(const short8*)&sB[(wn + 16 + fr) * 40 + fk];
    acc[0][0] = __builtin_amdgcn_mfma_f32_16x16x32_bf16(af0, bf0, acc[0][0], 0, 0, 0);
    acc[0][1] = __builtin_amdgcn_mfma_f32_16x16x32_bf16(af0, bf1, acc[0][1], 0, 0, 0);
    acc[1][0] = __builtin_amdgcn_mfma_f32_16x16x32_bf16(af1, bf0, acc[1][0], 0, 0, 0);
    acc[1][1] = __builtin_amdgcn_mfma_f32_16x16x32_bf16(af1, bf1, acc[1][1], 0, 0, 0);
    __syncthreads();
  }
#pragma unroll
  for (int i = 0; i < 2; i++)
#pragma unroll
    for (int j = 0; j < 2; j++)
#pragma unroll
      for (int q = 0; q < 4; q++) {
        int mm = m0 + wm + i * 16 + (lane >> 4) * 4 + q;
        int nn = n0 + wn + j * 16 + (lane & 15);
        if (mm < M) C[(size_t)mm * ldc + nn] = acc[i][j][q];
      }
}

// ---------------------------------------------------------------------------
// dt projection: bf16 MFMA, K=24 padded to 32, softplus epilogue
// ---------------------------------------------------------------------------
__global__ __launch_bounds__(256) void k_dtproj(const float* __restrict__ A,
                                                const float* __restrict__ W,
                                                const float* __restrict__ bias,
                                                float* __restrict__ C) {
  __shared__ short sA[64 * 40];
  __shared__ short sB[64 * 40];
  const int tid = threadIdx.x;
  const int m0 = blockIdx.x * 64, n0 = blockIdx.y * 64;
  const int srow = tid >> 2;
  const int skq = (tid & 3) * 8;
  const int lane = tid & 63, w = tid >> 6;
  const int wm = (w >> 1) * 32, wn = (w & 1) * 32;
  const int fr = lane & 15;
  const int fk = (lane >> 4) * 8;
  f32x4 acc[2][2] = {};
  const int am = m0 + srow;
  short8 av = {0, 0, 0, 0, 0, 0, 0, 0}, bv = {0, 0, 0, 0, 0, 0, 0, 0};
  if (skq < 24) {
    if (am < TT) {
      float4 a0 = *(const float4*)&A[(size_t)am * 56 + skq];
      float4 a1 = *(const float4*)&A[(size_t)am * 56 + skq + 4];
      av = short8{f2bf(a0.x), f2bf(a0.y), f2bf(a0.z), f2bf(a0.w),
                  f2bf(a1.x), f2bf(a1.y), f2bf(a1.z), f2bf(a1.w)};
    }
    float4 b0 = *(const float4*)&W[(size_t)(n0 + srow) * 24 + skq];
    float4 b1 = *(const float4*)&W[(size_t)(n0 + srow) * 24 + skq + 4];
    bv = short8{f2bf(b0.x), f2bf(b0.y), f2bf(b0.z), f2bf(b0.w),
                f2bf(b1.x), f2bf(b1.y), f2bf(b1.z), f2bf(b1.w)};
  }
  *(short8*)&sA[srow * 40 + skq] = av;
  *(short8*)&sB[srow * 40 + skq] = bv;
  __syncthreads();
  short8 af0 = *(const short8*)&sA[(wm + fr) * 40 + fk];
  short8 af1 = *(const short8*)&sA[(wm + 16 + fr) * 40 + fk];
  short8 bf0 = *(const short8*)&sB[(wn + fr) * 40 + fk];
  short8 bf1 = *(const short8*)&sB[(wn + 16 + fr) * 40 + fk];
  acc[0][0] = __builtin_amdgcn_mfma_f32_16x16x32_bf16(af0, bf0, acc[0][0], 0, 0, 0);
  acc[0][1] = __builtin_amdgcn_mfma_f32_16x16x32_bf16(af0, bf1, acc[0][1], 0, 0, 0);
  acc[1][0] = __builtin_amdgcn_mfma_f32_16x16x32_bf16(af1, bf0, acc[1][0], 0, 0, 0);
  acc[1][1] = __builtin_amdgcn_mfma_f32_16x16x32_bf16(af1, bf1, acc[1][1], 0, 0, 0);
#pragma unroll
  for (int i = 0; i < 2; i++)
#pragma unroll
    for (int j = 0; j < 2; j++)
#pragma unroll
      for (int q = 0; q < 4; q++) {
        int mm = m0 + wm + i * 16 + (lane >> 4) * 4 + q;
        int nn = n0 + wn + j * 16 + (lane & 15);
        if (mm < TT) {
          float v = acc[i][j][q] + bias[nn];
          v = (v > 20.f) ? v : log1pf(__expf(v));
          C[(size_t)mm * DI + nn] = v;
        }
      }
}

// ---------------------------------------------------------------------------
// x_proj: bf16 MFMA, BM=16, N=56 padded to 64, K=768
// ---------------------------------------------------------------------------
__global__ __launch_bounds__(256) void k_xproj(const float* __restrict__ A,
                                               const float* __restrict__ W,
                                               float* __restrict__ C) {
  __shared__ short sA[16 * 40];
  __shared__ short sB[64 * 40];
  const int tid = threadIdx.x;
  const int m0 = blockIdx.x * 16;
  const int lane = tid & 63, w = tid >> 6;
  const int wn = w * 16;
  const int fr = lane & 15;
  const int fk = (lane >> 4) * 8;
  const int srow = tid >> 2;
  const int skq = (tid & 3) * 8;
  f32x4 acc = {};
  for (int k0 = 0; k0 < DI; k0 += 32) {
    if (tid < 64) {
      float4 a0 = *(const float4*)&A[(size_t)(m0 + srow) * DI + k0 + skq];
      float4 a1 = *(const float4*)&A[(size_t)(m0 + srow) * DI + k0 + skq + 4];
      short8 av = {f2bf(a0.x), f2bf(a0.y), f2bf(a0.z), f2bf(a0.w),
                   f2bf(a1.x), f2bf(a1.y), f2bf(a1.z), f2bf(a1.w)};
      *(short8*)&sA[srow * 40 + skq] = av;
    }
    short8 bv = {0, 0, 0, 0, 0, 0, 0, 0};
    if (srow < 56) {
      float4 b0 = *(const float4*)&W[(size_t)srow * DI + k0 + skq];
      float4 b1 = *(const float4*)&W[(size_t)srow * DI + k0 + skq + 4];
      bv = short8{f2bf(b0.x), f2bf(b0.y), f2bf(b0.z), f2bf(b0.w),
                  f2bf(b1.x), f2bf(b1.y), f2bf(b1.z), f2bf(b1.w)};
    }
    *(short8*)&sB[srow * 40 + skq] = bv;
    __syncthreads();
    short8 af = *(const short8*)&sA[fr * 40 + fk];
    short8 bf = *(const short8*)&sB[(wn + fr) * 40 + fk];
    acc = __builtin_amdgcn_mfma_f32_16x16x32_bf16(af, bf, acc, 0, 0, 0);
    __syncthreads();
  }
#pragma unroll
  for (int q = 0; q < 4; q++) {
    int mm = m0 + (lane >> 4) * 4 + q;
    int nn = wn + (lane & 15);
    if (nn < 56) C[(size_t)mm * 56 + nn] = acc[q];
  }
}

// ---------------------------------------------------------------------------
// res += hid; u = LN(res) * nw + nb
// ---------------------------------------------------------------------------
__global__ __launch_bounds__(128) void k_addln(float* __restrict__ res,
                                               const float* __restrict__ hid,
                                               float* __restrict__ u,
                                               const float* __restrict__ nw,
                                               const float* __restrict__ nb) {
  const int t = blockIdx.x;
  const int tid = threadIdx.x;
  float r[3];
  float s = 0.f, sq = 0.f;
#pragma unroll
  for (int j = 0; j < 3; j++) {
    int d = tid + j * 128;
    float v = res[(size_t)t * DD + d] + hid[(size_t)t * DD + d];
    res[(size_t)t * DD + d] = v;
    r[j] = v;
    s += v; sq += v * v;
  }
#pragma unroll
  for (int o = 32; o > 0; o >>= 1) { s += __shfl_xor(s, o); sq += __shfl_xor(sq, o); }
  __shared__ float ls[2], lq[2];
  int w = tid >> 6;
  if ((tid & 63) == 0) { ls[w] = s; lq[w] = sq; }
  __syncthreads();
  float st = ls[0] + ls[1], qt = lq[0] + lq[1];
  float mu = st * (1.f / 384.f);
  float var = qt * (1.f / 384.f) - mu * mu;
  float rs = rsqrtf(var + EPSV);
#pragma unroll
  for (int j = 0; j < 3; j++) {
    int d = tid + j * 128;
    u[(size_t)t * DD + d] = (r[j] - mu) * rs * nw[d] + nb[d];
  }
}

// ---------------------------------------------------------------------------
// causal depthwise conv (k=4, left pad 3) + bias + SiLU
// ---------------------------------------------------------------------------
__global__ __launch_bounds__(256) void k_conv(const float* __restrict__ xz,
                                              const float* __restrict__ wc,
                                              const float* __restrict__ bc,
                                              float* __restrict__ xc) {
  int i = blockIdx.x * 256 + threadIdx.x;
  if (i >= TT * DI) return;
  int e = i % DI;
  int t = i / DI;
  int b = t / LL, l = t % LL;
  float4 w = *(const float4*)&wc[e * 4];
  float acc = bc[e];
  const float* base = xz + (size_t)(b * LL) * (2 * DI) + e;
  if (l >= 3) acc += base[(size_t)(l - 3) * (2 * DI)] * w.x;
  if (l >= 2) acc += base[(size_t)(l - 2) * (2 * DI)] * w.y;
  if (l >= 1) acc += base[(size_t)(l - 1) * (2 * DI)] * w.z;
  acc += base[(size_t)l * (2 * DI)] * w.w;
  xc[i] = acc * (1.f / (1.f + __expf(-acc)));
}

// ---------------------------------------------------------------------------
// chunked scan pass 1: fixed 16-token tiles (zero-padded), unrolled inner loop.
// Aprod computed as exp(A * sum(dt)) at the end.
// ---------------------------------------------------------------------------
__global__ __launch_bounds__(256) void k_scan1(const float* __restrict__ dt,
                                               const float* __restrict__ xc,
                                               const float* __restrict__ dbl,
                                               const float* __restrict__ Alog,
                                               float* __restrict__ Aprod,
                                               float* __restrict__ Hend) {
  __shared__ float sDt[16][16], sXc[16][16], sB[16][16];
  const int tid = threadIdx.x;
  const int n = tid & 15;
  const int es = tid >> 4;
  const int b = blockIdx.x / (DI / 16);
  const int eg = blockIdx.x % (DI / 16);
  const int c = blockIdx.y;
  const int e0 = eg * 16;
  const int e = e0 + es;
  const int tok = tid >> 4, idx = tid & 15;
  const float A = -__expf(Alog[(size_t)e * DSN + n]);
  float h = 0.f, dts = 0.f;
  const int l0 = c * CH;
  const int l1 = (c == NCHUNK - 1) ? LL : (l0 + CH);
  const size_t tbase = (size_t)b * LL;
  for (int lt = l0; lt < l1; lt += 16) {
    const int cnt = (l1 - lt < 16) ? (l1 - lt) : 16;
    float dv = 0.f, xv = 0.f, bvv = 0.f;
    if (tok < cnt) {
      size_t t = tbase + lt + tok;
      dv = dt[t * DI + e0 + idx];
      xv = xc[t * DI + e0 + idx];
      bvv = dbl[t * 56 + DTR + idx];
    }
    sDt[tok][idx] = dv; sXc[tok][idx] = xv; sB[tok][idx] = bvv;
    __syncthreads();
#pragma unroll
    for (int j = 0; j < 16; j++) {
      float dtv = sDt[j][es];
      float dA = __expf(dtv * A);
      h = dA * h + (dtv * sXc[j][es]) * sB[j][n];
      dts += dtv;
    }
    __syncthreads();
  }
  size_t ci = (((size_t)c * BB + b) * DI + e) * DSN + n;
  Aprod[ci] = __expf(dts * A);
  Hend[ci] = h;
}

// ---------------------------------------------------------------------------
// carry combine
// ---------------------------------------------------------------------------
__global__ __launch_bounds__(256) void k_scan_carry(const float* __restrict__ Aprod,
                                                    float* __restrict__ Hc) {
  int i = blockIdx.x * 256 + threadIdx.x;
  if (i >= BB * DI * DSN) return;
  const size_t stride = (size_t)BB * DI * DSN;
  float hin = 0.f;
#pragma unroll
  for (int c = 0; c < NCHUNK; c++) {
    size_t ci = (size_t)c * stride + i;
    float a = Aprod[ci];
    float he = Hc[ci];
    Hc[ci] = hin;
    hin = a * hin + he;
  }
}

// ---------------------------------------------------------------------------
// chunked scan pass 2: fixed 16-token tiles, unrolled; serial loop only
// produces contrib into LDS; gating epilogue vectorized per tile (z read
// direct from global). y aliases dt (same-block read-before-write per tile).
// ---------------------------------------------------------------------------
__global__ __launch_bounds__(256) void k_scan2(const float* __restrict__ dt,
                                               const float* __restrict__ xc,
                                               const float* __restrict__ xz,
                                               const float* __restrict__ dbl,
                                               const float* __restrict__ Alog,
                                               const float* __restrict__ Dp,
                                               const float* __restrict__ Hin,
                                               float* __restrict__ y) {
  __shared__ float sDt[16][16], sXc[16][16], sB[16][16], sC[16][16], sYc[16][16];
  const int tid = threadIdx.x;
  const int n = tid & 15;
  const int es = tid >> 4;
  const int b = blockIdx.x / (DI / 16);
  const int eg = blockIdx.x % (DI / 16);
  const int c = blockIdx.y;
  const int e0 = eg * 16;
  const int e = e0 + es;
  const int tok = tid >> 4, idx = tid & 15;
  const float A = -__expf(Alog[(size_t)e * DSN + n]);
  const float dpv = Dp[e0 + idx];
  size_t ci = (((size_t)c * BB + b) * DI + e) * DSN + n;
  float h = Hin[ci];
  const int l0 = c * CH;
  const int l1 = (c == NCHUNK - 1) ? LL : (l0 + CH);
  const size_t tbase = (size_t)b * LL;
  for (int lt = l0; lt < l1; lt += 16) {
    const int cnt = (l1 - lt < 16) ? (l1 - lt) : 16;
    float dv = 0.f, xv = 0.f, bvv = 0.f, cvv = 0.f;
    if (tok < cnt) {
      size_t t = tbase + lt + tok;
      dv = dt[t * DI + e0 + idx];
      xv = xc[t * DI + e0 + idx];
      bvv = dbl[t * 56 + DTR + idx];
      cvv = dbl[t * 56 + DTR + DSN + idx];
    }
    sDt[tok][idx] = dv; sXc[tok][idx] = xv; sB[tok][idx] = bvv; sC[tok][idx] = cvv;
    __syncthreads();
#pragma unroll
    for (int j = 0; j < 16; j++) {
      float dtv = sDt[j][es];
      float dA = __expf(dtv * A);
      h = dA * h + (dtv * sXc[j][es]) * sB[j][n];
      float contrib = h * sC[j][n];
#pragma unroll
      for (int o = 1; o < 16; o <<= 1) contrib += __shfl_xor(contrib, o);
      if (n == 0) sYc[j][es] = contrib;
    }
    __syncthreads();
    if (tok < cnt) {
      size_t t = tbase + lt + tok;
      float zv = xz[t * (2 * DI) + DI + e0 + idx];
      float sz = zv * (1.f / (1.f + __expf(-zv)));
      y[t * DI + e0 + idx] = (sYc[tok][idx] + sXc[tok][idx] * dpv) * sz;
    }
    __syncthreads();
  }
}

// ---------------------------------------------------------------------------
// final: LN(res[b,0]+hid[b,0]) -> head GEMM
// ---------------------------------------------------------------------------
__global__ __launch_bounds__(256) void k_final(const float* __restrict__ res,
                                               const float* __restrict__ hid,
                                               const float* __restrict__ nfw,
                                               const float* __restrict__ nfb,
                                               const float* __restrict__ hw,
                                               const float* __restrict__ hb,
                                               float* __restrict__ out) {
  const int b = blockIdx.x;
  const int tid = threadIdx.x;
  __shared__ float u0[DD];
  __shared__ float ls[4], lq[4];
  const size_t t0 = (size_t)b * LL * DD;
  float v0, v1 = 0.f;
  float s = 0.f, sq = 0.f;
  v0 = res[t0 + tid] + hid[t0 + tid];
  s += v0; sq += v0 * v0;
  if (tid < 128) {
    v1 = res[t0 + 256 + tid] + hid[t0 + 256 + tid];
    s += v1; sq += v1 * v1;
  }
#pragma unroll
  for (int o = 32; o > 0; o >>= 1) { s += __shfl_xor(s, o); sq += __shfl_xor(sq, o); }
  if ((tid & 63) == 0) { ls[tid >> 6] = s; lq[tid >> 6] = sq; }
  __syncthreads();
  float st = ls[0] + ls[1] + ls[2] + ls[3];
  float qt = lq[0] + lq[1] + lq[2] + lq[3];
  float mu = st * (1.f / 384.f);
  float var = qt * (1.f / 384.f) - mu * mu;
  float rs = rsqrtf(var + EPSV);
  u0[tid] = (v0 - mu) * rs * nfw[tid] + nfb[tid];
  if (tid < 128) u0[256 + tid] = (v1 - mu) * rs * nfw[256 + tid] + nfb[256 + tid];
  __syncthreads();
  for (int c = tid; c < NC; c += 256) {
    float acc = hb[c];
    const float* wrow = hw + (size_t)c * DD;
    for (int d = 0; d < DD; d += 4) {
      float4 w4 = *(const float4*)&wrow[d];
      acc += u0[d] * w4.x + u0[d + 1] * w4.y + u0[d + 2] * w4.z + u0[d + 3] * w4.w;
    }
    out[(size_t)b * NC + c] = acc;
  }
}

// ---------------------------------------------------------------------------
extern "C" void kernel_launch(void* const* d_in, const int* in_sizes, int n_in,
                              void* d_out, int out_size, void* d_ws, size_t ws_size,
                              hipStream_t stream) {
  const float* x       = (const float*)d_in[0];
  const float* patch_w = (const float*)d_in[1];
  const float* patch_b = (const float*)d_in[2];
  const float* cls     = (const float*)d_in[3];
  const float* pos     = (const float*)d_in[4];
  const float* in_proj = (const float*)d_in[5];
  const float* conv_w  = (const float*)d_in[6];
  const float* conv_b  = (const float*)d_in[7];
  const float* x_proj  = (const float*)d_in[8];
  const float* dt_w    = (const float*)d_in[9];
  const float* dt_b    = (const float*)d_in[10];
  const float* A_log   = (const float*)d_in[11];
  const float* D_ssm   = (const float*)d_in[12];
  const float* out_w   = (const float*)d_in[13];
  const float* norm_w  = (const float*)d_in[14];
  const float* norm_b  = (const float*)d_in[15];
  const float* normf_w = (const float*)d_in[16];
  const float* normf_b = (const float*)d_in[17];
  const float* head_w  = (const float*)d_in[18];
  const float* head_b  = (const float*)d_in[19];
  float* out = (float*)d_out;

  float* ws = (float*)d_ws;
  float* res = ws;  ws += (size_t)TT * DD;
  float* hid = ws;  ws += (size_t)TT * DD;
  float* u   = ws;  ws += (size_t)TT * DD;
  float* xzb = ws;  ws += (size_t)TT * 2 * DI;
  float* xcb = ws;  ws += (size_t)TT * DI;
  float* dbl = ws;  ws += (size_t)TT * 56;
  float* dtb = ws;  ws += (size_t)TT * DI;
  float* crg = ws;  ws += (size_t)TT * DI;   // 2*NCHUNK*BB*DI*DSN = 2.36M <= TT*DI
  float* yb  = dtb;                          // y aliases dt (same-block RAW order)
  float* Aprod = crg;
  float* Hc    = crg + (size_t)NCHUNK * BB * DI * DSN;

  k_init<<<(TT * DD + 255) / 256, 256, 0, stream>>>(cls, pos, res, hid);
  k_patch<<<dim3(49, 6), 256, 0, stream>>>(x, patch_w, patch_b, pos, hid);

  for (int layer = 0; layer < DEPTH; layer++) {
    k_addln<<<TT, 128, 0, stream>>>(res, hid, u, norm_w + layer * DD, norm_b + layer * DD);
    // in_proj: u (3152,384) @ Win^T (1536,384) -> xz (3152,1536)  [bf16 MFMA]
    k_gemm_mfma<<<dim3(50, 24), 256, 0, stream>>>(
        u, DD, in_proj + (size_t)layer * 2 * DI * DD, DD, xzb, 2 * DI, TT, 2 * DI, DD);
    k_conv<<<(TT * DI) / 256, 256, 0, stream>>>(xzb, conv_w + layer * DI * 4,
                                                conv_b + layer * DI, xcb);
    // x_proj: xc (3152,768) @ Wx^T (56,768) -> dbl (3152,56)  [bf16 MFMA]
    k_xproj<<<dim3(TT / 16), 256, 0, stream>>>(
        xcb, x_proj + (size_t)layer * 56 * DI, dbl);
    // dt: softplus(dbl[:, :24] @ Wdt^T + bdt) -> dt (3152,768)  [bf16 MFMA]
    k_dtproj<<<dim3(50, 12), 256, 0, stream>>>(
        dbl, dt_w + (size_t)layer * DI * DTR, dt_b + layer * DI, dtb);
    // chunked scan: pass1 -> carry -> pass2
    k_scan1<<<dim3(BB * (DI / 16), NCHUNK), 256, 0, stream>>>(
        dtb, xcb, dbl, A_log + (size_t)layer * DI * DSN, Aprod, Hc);
    k_scan_carry<<<(BB * DI * DSN + 255) / 256, 256, 0, stream>>>(Aprod, Hc);
    k_scan2<<<dim3(BB * (DI / 16), NCHUNK), 256, 0, stream>>>(
        dtb, xcb, xzb, dbl, A_log + (size_t)layer * DI * DSN,
        D_ssm + layer * DI, Hc, yb);
    // out_proj: y (3152,768) @ Wout^T (384,768) -> hid (3152,384)  [bf16 MFMA]
    k_gemm_mfma<<<dim3(50, 6), 256, 0, stream>>>(
        yb, DI, out_w + (size_t)layer * DD * DI, DI, hid, DD, TT, DD, DI);
  }

  k_final<<<BB, 256, 0, stream>>>(res, hid, normf_w, normf_b, head_w, head_b, out);
}

// Round 6
// 3554.173 us; speedup vs baseline: 1.1618x; 1.1618x over previous
//
#include <hip/hip_runtime.h>
#include <hip/hip_bf16.h>
#include <math.h>

// Model dims
#define BB     16
#define LL     197
#define DD     384
#define DEPTH  24
#define DI     768
#define DSN    16
#define DTR    24
#define NC     1000
#define TT     (BB*LL)      // 3152 tokens
#define NPATCH 196
#define EPSV   1e-5f

// chunked scan config: 12 chunks of 17 tokens (11*17=187, last=10)
#define NCHUNK 12
#define CH     17

typedef __attribute__((ext_vector_type(8))) short short8;
typedef __attribute__((ext_vector_type(4))) float f32x4;

__device__ __forceinline__ short f2bf(float f) {
  union { float f; unsigned u; } v; v.f = f;
  unsigned u = v.u + 0x7fffu + ((v.u >> 16) & 1u);
  return (short)(u >> 16);
}

// ---------------------------------------------------------------------------
// init
// ---------------------------------------------------------------------------
__global__ __launch_bounds__(256) void k_init(const float* __restrict__ cls,
                                              const float* __restrict__ pos,
                                              float* __restrict__ res,
                                              float* __restrict__ hid) {
  int i = blockIdx.x * 256 + threadIdx.x;
  if (i < TT * DD) res[i] = 0.f;
  if (i < BB * DD) {
    int b = i / DD, d = i % DD;
    hid[(size_t)(b * LL) * DD + d] = cls[d] + pos[d];
  }
}

// ---------------------------------------------------------------------------
// patch embed: bf16 MFMA GEMM with fused im2col.
// ---------------------------------------------------------------------------
__global__ __launch_bounds__(256) void k_patch(const float* __restrict__ x,
                                               const float* __restrict__ pw,
                                               const float* __restrict__ pb,
                                               const float* __restrict__ pos,
                                               float* __restrict__ hid) {
  __shared__ short sA[64 * 40];
  __shared__ short sB[64 * 40];
  const int tid = threadIdx.x;
  const int m0 = blockIdx.x * 64, n0 = blockIdx.y * 64;
  const int srow = tid >> 2;
  const int skq = (tid & 3) * 8;
  const int lane = tid & 63, w = tid >> 6;
  const int wm = (w >> 1) * 32, wn = (w & 1) * 32;
  const int fr = lane & 15;
  const int fk = (lane >> 4) * 8;
  f32x4 acc[2][2] = {};
  const int m = m0 + srow;
  const int b = m / NPATCH;
  const int p = m % NPATCH;
  const int ph = p / 14, pwi = p % 14;
  const float* Wrow = pw + (size_t)(n0 + srow) * 768 + skq;
  for (int k0 = 0; k0 < 768; k0 += 32) {
    int k = k0 + skq;
    int c = k >> 8, rr = (k >> 4) & 15, kw = k & 15;
    const float* xrow = &x[(size_t)(((b * 3 + c) * 224) + (ph * 16 + rr)) * 224 +
                           (pwi * 16 + kw)];
    float4 a0 = *(const float4*)&xrow[0];
    float4 a1 = *(const float4*)&xrow[4];
    float4 b0 = *(const float4*)&Wrow[k0];
    float4 b1 = *(const float4*)&Wrow[k0 + 4];
    short8 av = {f2bf(a0.x), f2bf(a0.y), f2bf(a0.z), f2bf(a0.w),
                 f2bf(a1.x), f2bf(a1.y), f2bf(a1.z), f2bf(a1.w)};
    short8 bv = {f2bf(b0.x), f2bf(b0.y), f2bf(b0.z), f2bf(b0.w),
                 f2bf(b1.x), f2bf(b1.y), f2bf(b1.z), f2bf(b1.w)};
    *(short8*)&sA[srow * 40 + skq] = av;
    *(short8*)&sB[srow * 40 + skq] = bv;
    __syncthreads();
    short8 af0 = *(const short8*)&sA[(wm + fr) * 40 + fk];
    short8 af1 = *(const short8*)&sA[(wm + 16 + fr) * 40 + fk];
    short8 bf0 = *(const short8*)&sB[(wn + fr) * 40 + fk];
    short8 bf1 = *(const short8*)&sB[(wn + 16 + fr) * 40 + fk];
    acc[0][0] = __builtin_amdgcn_mfma_f32_16x16x32_bf16(af0, bf0, acc[0][0], 0, 0, 0);
    acc[0][1] = __builtin_amdgcn_mfma_f32_16x16x32_bf16(af0, bf1, acc[0][1], 0, 0, 0);
    acc[1][0] = __builtin_amdgcn_mfma_f32_16x16x32_bf16(af1, bf0, acc[1][0], 0, 0, 0);
    acc[1][1] = __builtin_amdgcn_mfma_f32_16x16x32_bf16(af1, bf1, acc[1][1], 0, 0, 0);
    __syncthreads();
  }
#pragma unroll
  for (int i = 0; i < 2; i++)
#pragma unroll
    for (int j = 0; j < 2; j++)
#pragma unroll
      for (int q = 0; q < 4; q++) {
        int mm = m0 + wm + i * 16 + (lane >> 4) * 4 + q;
        int nn = n0 + wn + j * 16 + (lane & 15);
        int b2 = mm / NPATCH, pp = mm % NPATCH;
        int tok = b2 * LL + 1 + pp;
        hid[(size_t)tok * DD + nn] = acc[i][j][q] + pb[nn] + pos[(size_t)(1 + pp) * DD + nn];
      }
}

// ---------------------------------------------------------------------------
// bf16 MFMA GEMM: C[M,N] = A[M,K] * W[N,K]^T
// ---------------------------------------------------------------------------
__global__ __launch_bounds__(256) void k_gemm_mfma(const float* __restrict__ A, int lda,
                                                   const float* __restrict__ W, int ldb,
                                                   float* __restrict__ C, int ldc,
                                                   int M, int N, int K) {
  __shared__ short sA[64 * 40];
  __shared__ short sB[64 * 40];
  const int tid = threadIdx.x;
  const int m0 = blockIdx.x * 64, n0 = blockIdx.y * 64;
  const int srow = tid >> 2;
  const int skq = (tid & 3) * 8;
  const int lane = tid & 63, w = tid >> 6;
  const int wm = (w >> 1) * 32, wn = (w & 1) * 32;
  const int fr = lane & 15;
  const int fk = (lane >> 4) * 8;
  f32x4 acc[2][2] = {};
  const int am = m0 + srow;
  const bool aok = am < M;
  const float* Arow = A + (size_t)am * lda + skq;
  const float* Wrow = W + (size_t)(n0 + srow) * ldb + skq;
  for (int k0 = 0; k0 < K; k0 += 32) {
    float4 a0 = {0, 0, 0, 0}, a1 = {0, 0, 0, 0};
    if (aok) {
      a0 = *(const float4*)&Arow[k0];
      a1 = *(const float4*)&Arow[k0 + 4];
    }
    float4 b0 = *(const float4*)&Wrow[k0];
    float4 b1 = *(const float4*)&Wrow[k0 + 4];
    short8 av = {f2bf(a0.x), f2bf(a0.y), f2bf(a0.z), f2bf(a0.w),
                 f2bf(a1.x), f2bf(a1.y), f2bf(a1.z), f2bf(a1.w)};
    short8 bv = {f2bf(b0.x), f2bf(b0.y), f2bf(b0.z), f2bf(b0.w),
                 f2bf(b1.x), f2bf(b1.y), f2bf(b1.z), f2bf(b1.w)};
    *(short8*)&sA[srow * 40 + skq] = av;
    *(short8*)&sB[srow * 40 + skq] = bv;
    __syncthreads();
    short8 af0 = *(const short8*)&sA[(wm + fr) * 40 + fk];
    short8 af1 = *(const short8*)&sA[(wm + 16 + fr) * 40 + fk];
    short8 bf0 = *(const short8*)&sB[(wn + fr) * 40 + fk];
    short8 bf1 = *(const short8*)&sB[(wn + 16 + fr) * 40 + fk];
    acc[0][0] = __builtin_amdgcn_mfma_f32_16x16x32_bf16(af0, bf0, acc[0][0], 0, 0, 0);
    acc[0][1] = __builtin_amdgcn_mfma_f32_16x16x32_bf16(af0, bf1, acc[0][1], 0, 0, 0);
    acc[1][0] = __builtin_amdgcn_mfma_f32_16x16x32_bf16(af1, bf0, acc[1][0], 0, 0, 0);
    acc[1][1] = __builtin_amdgcn_mfma_f32_16x16x32_bf16(af1, bf1, acc[1][1], 0, 0, 0);
    __syncthreads();
  }
#pragma unroll
  for (int i = 0; i < 2; i++)
#pragma unroll
    for (int j = 0; j < 2; j++)
#pragma unroll
      for (int q = 0; q < 4; q++) {
        int mm = m0 + wm + i * 16 + (lane >> 4) * 4 + q;
        int nn = n0 + wn + j * 16 + (lane & 15);
        if (mm < M) C[(size_t)mm * ldc + nn] = acc[i][j][q];
      }
}

// ---------------------------------------------------------------------------
// dt projection: bf16 MFMA, K=24 padded to 32, softplus epilogue
// ---------------------------------------------------------------------------
__global__ __launch_bounds__(256) void k_dtproj(const float* __restrict__ A,
                                                const float* __restrict__ W,
                                                const float* __restrict__ bias,
                                                float* __restrict__ C) {
  __shared__ short sA[64 * 40];
  __shared__ short sB[64 * 40];
  const int tid = threadIdx.x;
  const int m0 = blockIdx.x * 64, n0 = blockIdx.y * 64;
  const int srow = tid >> 2;
  const int skq = (tid & 3) * 8;
  const int lane = tid & 63, w = tid >> 6;
  const int wm = (w >> 1) * 32, wn = (w & 1) * 32;
  const int fr = lane & 15;
  const int fk = (lane >> 4) * 8;
  f32x4 acc[2][2] = {};
  const int am = m0 + srow;
  short8 av = {0, 0, 0, 0, 0, 0, 0, 0}, bv = {0, 0, 0, 0, 0, 0, 0, 0};
  if (skq < 24) {
    if (am < TT) {
      float4 a0 = *(const float4*)&A[(size_t)am * 56 + skq];
      float4 a1 = *(const float4*)&A[(size_t)am * 56 + skq + 4];
      av = short8{f2bf(a0.x), f2bf(a0.y), f2bf(a0.z), f2bf(a0.w),
                  f2bf(a1.x), f2bf(a1.y), f2bf(a1.z), f2bf(a1.w)};
    }
    float4 b0 = *(const float4*)&W[(size_t)(n0 + srow) * 24 + skq];
    float4 b1 = *(const float4*)&W[(size_t)(n0 + srow) * 24 + skq + 4];
    bv = short8{f2bf(b0.x), f2bf(b0.y), f2bf(b0.z), f2bf(b0.w),
                f2bf(b1.x), f2bf(b1.y), f2bf(b1.z), f2bf(b1.w)};
  }
  *(short8*)&sA[srow * 40 + skq] = av;
  *(short8*)&sB[srow * 40 + skq] = bv;
  __syncthreads();
  short8 af0 = *(const short8*)&sA[(wm + fr) * 40 + fk];
  short8 af1 = *(const short8*)&sA[(wm + 16 + fr) * 40 + fk];
  short8 bf0 = *(const short8*)&sB[(wn + fr) * 40 + fk];
  short8 bf1 = *(const short8*)&sB[(wn + 16 + fr) * 40 + fk];
  acc[0][0] = __builtin_amdgcn_mfma_f32_16x16x32_bf16(af0, bf0, acc[0][0], 0, 0, 0);
  acc[0][1] = __builtin_amdgcn_mfma_f32_16x16x32_bf16(af0, bf1, acc[0][1], 0, 0, 0);
  acc[1][0] = __builtin_amdgcn_mfma_f32_16x16x32_bf16(af1, bf0, acc[1][0], 0, 0, 0);
  acc[1][1] = __builtin_amdgcn_mfma_f32_16x16x32_bf16(af1, bf1, acc[1][1], 0, 0, 0);
#pragma unroll
  for (int i = 0; i < 2; i++)
#pragma unroll
    for (int j = 0; j < 2; j++)
#pragma unroll
      for (int q = 0; q < 4; q++) {
        int mm = m0 + wm + i * 16 + (lane >> 4) * 4 + q;
        int nn = n0 + wn + j * 16 + (lane & 15);
        if (mm < TT) {
          float v = acc[i][j][q] + bias[nn];
          v = (v > 20.f) ? v : log1pf(__expf(v));
          C[(size_t)mm * DI + nn] = v;
        }
      }
}

// ---------------------------------------------------------------------------
// x_proj: bf16 MFMA, BM=16, N=56 padded to 64, K=768
// ---------------------------------------------------------------------------
__global__ __launch_bounds__(256) void k_xproj(const float* __restrict__ A,
                                               const float* __restrict__ W,
                                               float* __restrict__ C) {
  __shared__ short sA[16 * 40];
  __shared__ short sB[64 * 40];
  const int tid = threadIdx.x;
  const int m0 = blockIdx.x * 16;
  const int lane = tid & 63, w = tid >> 6;
  const int wn = w * 16;
  const int fr = lane & 15;
  const int fk = (lane >> 4) * 8;
  const int srow = tid >> 2;
  const int skq = (tid & 3) * 8;
  f32x4 acc = {};
  for (int k0 = 0; k0 < DI; k0 += 32) {
    if (tid < 64) {
      float4 a0 = *(const float4*)&A[(size_t)(m0 + srow) * DI + k0 + skq];
      float4 a1 = *(const float4*)&A[(size_t)(m0 + srow) * DI + k0 + skq + 4];
      short8 av = {f2bf(a0.x), f2bf(a0.y), f2bf(a0.z), f2bf(a0.w),
                   f2bf(a1.x), f2bf(a1.y), f2bf(a1.z), f2bf(a1.w)};
      *(short8*)&sA[srow * 40 + skq] = av;
    }
    short8 bv = {0, 0, 0, 0, 0, 0, 0, 0};
    if (srow < 56) {
      float4 b0 = *(const float4*)&W[(size_t)srow * DI + k0 + skq];
      float4 b1 = *(const float4*)&W[(size_t)srow * DI + k0 + skq + 4];
      bv = short8{f2bf(b0.x), f2bf(b0.y), f2bf(b0.z), f2bf(b0.w),
                  f2bf(b1.x), f2bf(b1.y), f2bf(b1.z), f2bf(b1.w)};
    }
    *(short8*)&sB[srow * 40 + skq] = bv;
    __syncthreads();
    short8 af = *(const short8*)&sA[fr * 40 + fk];
    short8 bf = *(const short8*)&sB[(wn + fr) * 40 + fk];
    acc = __builtin_amdgcn_mfma_f32_16x16x32_bf16(af, bf, acc, 0, 0, 0);
    __syncthreads();
  }
#pragma unroll
  for (int q = 0; q < 4; q++) {
    int mm = m0 + (lane >> 4) * 4 + q;
    int nn = wn + (lane & 15);
    if (nn < 56) C[(size_t)mm * 56 + nn] = acc[q];
  }
}

// ---------------------------------------------------------------------------
// res += hid; u = LN(res) * nw + nb
// ---------------------------------------------------------------------------
__global__ __launch_bounds__(128) void k_addln(float* __restrict__ res,
                                               const float* __restrict__ hid,
                                               float* __restrict__ u,
                                               const float* __restrict__ nw,
                                               const float* __restrict__ nb) {
  const int t = blockIdx.x;
  const int tid = threadIdx.x;
  float r[3];
  float s = 0.f, sq = 0.f;
#pragma unroll
  for (int j = 0; j < 3; j++) {
    int d = tid + j * 128;
    float v = res[(size_t)t * DD + d] + hid[(size_t)t * DD + d];
    res[(size_t)t * DD + d] = v;
    r[j] = v;
    s += v; sq += v * v;
  }
#pragma unroll
  for (int o = 32; o > 0; o >>= 1) { s += __shfl_xor(s, o); sq += __shfl_xor(sq, o); }
  __shared__ float ls[2], lq[2];
  int w = tid >> 6;
  if ((tid & 63) == 0) { ls[w] = s; lq[w] = sq; }
  __syncthreads();
  float st = ls[0] + ls[1], qt = lq[0] + lq[1];
  float mu = st * (1.f / 384.f);
  float var = qt * (1.f / 384.f) - mu * mu;
  float rs = rsqrtf(var + EPSV);
#pragma unroll
  for (int j = 0; j < 3; j++) {
    int d = tid + j * 128;
    u[(size_t)t * DD + d] = (r[j] - mu) * rs * nw[d] + nb[d];
  }
}

// ---------------------------------------------------------------------------
// causal depthwise conv (k=4, left pad 3) + bias + SiLU
// ---------------------------------------------------------------------------
__global__ __launch_bounds__(256) void k_conv(const float* __restrict__ xz,
                                              const float* __restrict__ wc,
                                              const float* __restrict__ bc,
                                              float* __restrict__ xc) {
  int i = blockIdx.x * 256 + threadIdx.x;
  if (i >= TT * DI) return;
  int e = i % DI;
  int t = i / DI;
  int b = t / LL, l = t % LL;
  float4 w = *(const float4*)&wc[e * 4];
  float acc = bc[e];
  const float* base = xz + (size_t)(b * LL) * (2 * DI) + e;
  if (l >= 3) acc += base[(size_t)(l - 3) * (2 * DI)] * w.x;
  if (l >= 2) acc += base[(size_t)(l - 2) * (2 * DI)] * w.y;
  if (l >= 1) acc += base[(size_t)(l - 1) * (2 * DI)] * w.z;
  acc += base[(size_t)l * (2 * DI)] * w.w;
  xc[i] = acc * (1.f / (1.f + __expf(-acc)));
}

// ---------------------------------------------------------------------------
// NEW scan: register-resident h[8] per thread, thread = (b, e, n-half).
// No LDS, no barriers, single pair-shfl in pass2.
// Block covers 128 e x 2 nh; grid = (DI/128, BB, NCHUNK).
// ---------------------------------------------------------------------------
__global__ __launch_bounds__(256) void k_scan1(const float* __restrict__ dt,
                                               const float* __restrict__ xc,
                                               const float* __restrict__ dbl,
                                               const float* __restrict__ Alog,
                                               float* __restrict__ Aprod,
                                               float* __restrict__ Hend) {
  const int tid = threadIdx.x;
  const int e = blockIdx.x * 128 + (tid >> 1);
  const int nh = tid & 1;
  const int b = blockIdx.y;
  const int c = blockIdx.z;
  // negA[j] = -exp(Alog[e][nh*8+j])
  float4 al0 = *(const float4*)&Alog[(size_t)e * DSN + nh * 8];
  float4 al1 = *(const float4*)&Alog[(size_t)e * DSN + nh * 8 + 4];
  float negA[8] = {-__expf(al0.x), -__expf(al0.y), -__expf(al0.z), -__expf(al0.w),
                   -__expf(al1.x), -__expf(al1.y), -__expf(al1.z), -__expf(al1.w)};
  float h[8] = {};
  float asum = 0.f;
  const int l0 = c * CH;
  const int l1 = (l0 + CH < LL) ? (l0 + CH) : LL;
  const size_t tbase = (size_t)b * LL;
  for (int l = l0; l < l1; l++) {
    size_t t = tbase + l;
    float dtv = dt[t * DI + e];
    float xcv = xc[t * DI + e];
    float4 B0 = *(const float4*)&dbl[t * 56 + DTR + nh * 8];
    float4 B1 = *(const float4*)&dbl[t * 56 + DTR + nh * 8 + 4];
    float dx = dtv * xcv;
    float Bv[8] = {B0.x, B0.y, B0.z, B0.w, B1.x, B1.y, B1.z, B1.w};
#pragma unroll
    for (int j = 0; j < 8; j++)
      h[j] = __expf(dtv * negA[j]) * h[j] + dx * Bv[j];
    asum += dtv;
  }
  size_t ci = (((size_t)c * BB + b) * DI + e) * DSN + nh * 8;
  float4 ap0 = {__expf(asum * negA[0]), __expf(asum * negA[1]),
                __expf(asum * negA[2]), __expf(asum * negA[3])};
  float4 ap1 = {__expf(asum * negA[4]), __expf(asum * negA[5]),
                __expf(asum * negA[6]), __expf(asum * negA[7])};
  *(float4*)&Aprod[ci] = ap0;
  *(float4*)&Aprod[ci + 4] = ap1;
  *(float4*)&Hend[ci] = float4{h[0], h[1], h[2], h[3]};
  *(float4*)&Hend[ci + 4] = float4{h[4], h[5], h[6], h[7]};
}

// ---------------------------------------------------------------------------
// carry combine over NCHUNK chunks, per (b,e,n)
// ---------------------------------------------------------------------------
__global__ __launch_bounds__(256) void k_scan_carry(const float* __restrict__ Aprod,
                                                    float* __restrict__ Hc) {
  int i = blockIdx.x * 256 + threadIdx.x;
  if (i >= BB * DI * DSN) return;
  const size_t stride = (size_t)BB * DI * DSN;
  float hin = 0.f;
#pragma unroll
  for (int c = 0; c < NCHUNK; c++) {
    size_t ci = (size_t)c * stride + i;
    float a = Aprod[ci];
    float he = Hc[ci];
    Hc[ci] = hin;
    hin = a * hin + he;
  }
}

// ---------------------------------------------------------------------------
// scan pass 2: register h[8], per-token y via 8 fma + one pair shfl.
// y aliases dt (same-thread read-before-write per (t,e)).
// ---------------------------------------------------------------------------
__global__ __launch_bounds__(256) void k_scan2(const float* __restrict__ dt,
                                               const float* __restrict__ xc,
                                               const float* __restrict__ xz,
                                               const float* __restrict__ dbl,
                                               const float* __restrict__ Alog,
                                               const float* __restrict__ Dp,
                                               const float* __restrict__ Hin,
                                               float* __restrict__ y) {
  const int tid = threadIdx.x;
  const int e = blockIdx.x * 128 + (tid >> 1);
  const int nh = tid & 1;
  const int b = blockIdx.y;
  const int c = blockIdx.z;
  float4 al0 = *(const float4*)&Alog[(size_t)e * DSN + nh * 8];
  float4 al1 = *(const float4*)&Alog[(size_t)e * DSN + nh * 8 + 4];
  float negA[8] = {-__expf(al0.x), -__expf(al0.y), -__expf(al0.z), -__expf(al0.w),
                   -__expf(al1.x), -__expf(al1.y), -__expf(al1.z), -__expf(al1.w)};
  const float dpv = Dp[e];
  size_t ci = (((size_t)c * BB + b) * DI + e) * DSN + nh * 8;
  float4 h0 = *(const float4*)&Hin[ci];
  float4 h1 = *(const float4*)&Hin[ci + 4];
  float h[8] = {h0.x, h0.y, h0.z, h0.w, h1.x, h1.y, h1.z, h1.w};
  const int l0 = c * CH;
  const int l1 = (l0 + CH < LL) ? (l0 + CH) : LL;
  const size_t tbase = (size_t)b * LL;
  for (int l = l0; l < l1; l++) {
    size_t t = tbase + l;
    float dtv = dt[t * DI + e];
    float xcv = xc[t * DI + e];
    float zv = xz[t * (2 * DI) + DI + e];
    float4 B0 = *(const float4*)&dbl[t * 56 + DTR + nh * 8];
    float4 B1 = *(const float4*)&dbl[t * 56 + DTR + nh * 8 + 4];
    float4 C0 = *(const float4*)&dbl[t * 56 + DTR + DSN + nh * 8];
    float4 C1 = *(const float4*)&dbl[t * 56 + DTR + DSN + nh * 8 + 4];
    float dx = dtv * xcv;
    float Bv[8] = {B0.x, B0.y, B0.z, B0.w, B1.x, B1.y, B1.z, B1.w};
    float Cv[8] = {C0.x, C0.y, C0.z, C0.w, C1.x, C1.y, C1.z, C1.w};
    float acc = 0.f;
#pragma unroll
    for (int j = 0; j < 8; j++) {
      h[j] = __expf(dtv * negA[j]) * h[j] + dx * Bv[j];
      acc += h[j] * Cv[j];
    }
    acc += __shfl_xor(acc, 1);   // combine the two n-halves
    if (nh == 0) {
      float sz = zv * (1.f / (1.f + __expf(-zv)));
      y[t * DI + e] = (acc + xcv * dpv) * sz;
    }
  }
}

// ---------------------------------------------------------------------------
// final: LN(res[b,0]+hid[b,0]) -> head GEMM
// ---------------------------------------------------------------------------
__global__ __launch_bounds__(256) void k_final(const float* __restrict__ res,
                                               const float* __restrict__ hid,
                                               const float* __restrict__ nfw,
                                               const float* __restrict__ nfb,
                                               const float* __restrict__ hw,
                                               const float* __restrict__ hb,
                                               float* __restrict__ out) {
  const int b = blockIdx.x;
  const int tid = threadIdx.x;
  __shared__ float u0[DD];
  __shared__ float ls[4], lq[4];
  const size_t t0 = (size_t)b * LL * DD;
  float v0, v1 = 0.f;
  float s = 0.f, sq = 0.f;
  v0 = res[t0 + tid] + hid[t0 + tid];
  s += v0; sq += v0 * v0;
  if (tid < 128) {
    v1 = res[t0 + 256 + tid] + hid[t0 + 256 + tid];
    s += v1; sq += v1 * v1;
  }
#pragma unroll
  for (int o = 32; o > 0; o >>= 1) { s += __shfl_xor(s, o); sq += __shfl_xor(sq, o); }
  if ((tid & 63) == 0) { ls[tid >> 6] = s; lq[tid >> 6] = sq; }
  __syncthreads();
  float st = ls[0] + ls[1] + ls[2] + ls[3];
  float qt = lq[0] + lq[1] + lq[2] + lq[3];
  float mu = st * (1.f / 384.f);
  float var = qt * (1.f / 384.f) - mu * mu;
  float rs = rsqrtf(var + EPSV);
  u0[tid] = (v0 - mu) * rs * nfw[tid] + nfb[tid];
  if (tid < 128) u0[256 + tid] = (v1 - mu) * rs * nfw[256 + tid] + nfb[256 + tid];
  __syncthreads();
  for (int c = tid; c < NC; c += 256) {
    float acc = hb[c];
    const float* wrow = hw + (size_t)c * DD;
    for (int d = 0; d < DD; d += 4) {
      float4 w4 = *(const float4*)&wrow[d];
      acc += u0[d] * w4.x + u0[d + 1] * w4.y + u0[d + 2] * w4.z + u0[d + 3] * w4.w;
    }
    out[(size_t)b * NC + c] = acc;
  }
}

// ---------------------------------------------------------------------------
extern "C" void kernel_launch(void* const* d_in, const int* in_sizes, int n_in,
                              void* d_out, int out_size, void* d_ws, size_t ws_size,
                              hipStream_t stream) {
  const float* x       = (const float*)d_in[0];
  const float* patch_w = (const float*)d_in[1];
  const float* patch_b = (const float*)d_in[2];
  const float* cls     = (const float*)d_in[3];
  const float* pos     = (const float*)d_in[4];
  const float* in_proj = (const float*)d_in[5];
  const float* conv_w  = (const float*)d_in[6];
  const float* conv_b  = (const float*)d_in[7];
  const float* x_proj  = (const float*)d_in[8];
  const float* dt_w    = (const float*)d_in[9];
  const float* dt_b    = (const float*)d_in[10];
  const float* A_log   = (const float*)d_in[11];
  const float* D_ssm   = (const float*)d_in[12];
  const float* out_w   = (const float*)d_in[13];
  const float* norm_w  = (const float*)d_in[14];
  const float* norm_b  = (const float*)d_in[15];
  const float* normf_w = (const float*)d_in[16];
  const float* normf_b = (const float*)d_in[17];
  const float* head_w  = (const float*)d_in[18];
  const float* head_b  = (const float*)d_in[19];
  float* out = (float*)d_out;

  float* ws = (float*)d_ws;
  float* res = ws;  ws += (size_t)TT * DD;
  float* hid = ws;  ws += (size_t)TT * DD;
  float* u   = ws;  ws += (size_t)TT * DD;
  float* xzb = ws;  ws += (size_t)TT * 2 * DI;
  float* xcb = ws;  ws += (size_t)TT * DI;
  float* dbl = ws;  ws += (size_t)TT * 56;
  float* dtb = ws;  ws += (size_t)TT * DI;
  float* crg = ws;  ws += (size_t)TT * DI;
  float* yb  = dtb;   // y aliases dt (same-thread RAW order per (t,e))
  // Aprod: NCHUNK*BB*DI*DSN = 2.36M floats <= crg cap (TT*DI = 2.42M)
  float* Aprod = crg;
  // Hc reuses hid+u (contiguous, 2.42M floats): hid/u are dead between
  // in_proj (consumes u) and out_proj (writes hid) within a layer.
  float* Hc = hid;

  k_init<<<(TT * DD + 255) / 256, 256, 0, stream>>>(cls, pos, res, hid);
  k_patch<<<dim3(49, 6), 256, 0, stream>>>(x, patch_w, patch_b, pos, hid);

  for (int layer = 0; layer < DEPTH; layer++) {
    k_addln<<<TT, 128, 0, stream>>>(res, hid, u, norm_w + layer * DD, norm_b + layer * DD);
    // in_proj: u (3152,384) @ Win^T (1536,384) -> xz (3152,1536)  [bf16 MFMA]
    k_gemm_mfma<<<dim3(50, 24), 256, 0, stream>>>(
        u, DD, in_proj + (size_t)layer * 2 * DI * DD, DD, xzb, 2 * DI, TT, 2 * DI, DD);
    k_conv<<<(TT * DI) / 256, 256, 0, stream>>>(xzb, conv_w + layer * DI * 4,
                                                conv_b + layer * DI, xcb);
    // x_proj: xc (3152,768) @ Wx^T (56,768) -> dbl (3152,56)  [bf16 MFMA]
    k_xproj<<<dim3(TT / 16), 256, 0, stream>>>(
        xcb, x_proj + (size_t)layer * 56 * DI, dbl);
    // dt: softplus(dbl[:, :24] @ Wdt^T + bdt) -> dt (3152,768)  [bf16 MFMA]
    k_dtproj<<<dim3(50, 12), 256, 0, stream>>>(
        dbl, dt_w + (size_t)layer * DI * DTR, dt_b + layer * DI, dtb);
    // chunked scan: pass1 -> carry -> pass2  (register-h, shfl-free)
    k_scan1<<<dim3(DI / 128, BB, NCHUNK), 256, 0, stream>>>(
        dtb, xcb, dbl, A_log + (size_t)layer * DI * DSN, Aprod, Hc);
    k_scan_carry<<<(BB * DI * DSN + 255) / 256, 256, 0, stream>>>(Aprod, Hc);
    k_scan2<<<dim3(DI / 128, BB, NCHUNK), 256, 0, stream>>>(
        dtb, xcb, xzb, dbl, A_log + (size_t)layer * DI * DSN,
        D_ssm + layer * DI, Hc, yb);
    // out_proj: y (3152,768) @ Wout^T (384,768) -> hid (3152,384)  [bf16 MFMA]
    k_gemm_mfma<<<dim3(50, 6), 256, 0, stream>>>(
        yb, DI, out_w + (size_t)layer * DD * DI, DI, hid, DD, TT, DD, DI);
  }

  k_final<<<BB, 256, 0, stream>>>(res, hid, normf_w, normf_b, head_w, head_b, out);
}